// Round 7
// baseline (111.131 us; speedup 1.0000x reference)
//
#include <hip/hip_runtime.h>
#include <stdint.h>

// Problem constants (from reference setup_inputs)
#define BATCH 4096
#define ISZ   512
#define OSZ   512
#define KDIM  4096           // contraction dim: k = i*8 + d

// GEMM tiling
#define TM 128
#define TN 128
#define BK 64
#define SPLITK 4

typedef __bf16 bf16x8 __attribute__((ext_vector_type(8)));
typedef float  f32x4  __attribute__((ext_vector_type(4)));

__device__ __forceinline__ unsigned short f2bf(float f) {
    uint32_t u = __float_as_uint(f);
    u = (u + 0x7FFFu + ((u >> 16) & 1u)) >> 16;
    return (unsigned short)u;
}

// flat fp32 -> bf16 convert (coef already k-contiguous: [O][I][D] -> [O][K])
__global__ __launch_bounds__(256) void convert_bf16(
    const float* __restrict__ src, unsigned short* __restrict__ dst, int n4)
{
    int idx = blockIdx.x * 256 + threadIdx.x;
    if (idx >= n4) return;
    float4 v = reinterpret_cast<const float4*>(src)[idx];
    uint2 o;
    o.x = (uint32_t)f2bf(v.x) | ((uint32_t)f2bf(v.y) << 16);
    o.y = (uint32_t)f2bf(v.z) | ((uint32_t)f2bf(v.w) << 16);
    reinterpret_cast<uint2*>(dst)[idx] = o;
}

// Fused Jacobi + GEMM, bf16 split-K partials with plain stores.
// Evolution: R3 atomics -> ~50us TCC serialization (removed). R5 in-register
// A -> 2x VALU + dependent chain (reverted). R6 A+B both through LDS ->
// LDS-BW bound (~96 KB/block/iter through one 204 GB/s pipe ~ 2x MFMA time).
// R7: B never touches LDS. B-fragment = 16 contiguous bytes of k-major coefb
// (lane l: B[n=l&15][k=(l>>4)*8+j]) -> per-lane global_load_dwordx4 from L2
// (coefb = 4 MB, L2-resident; wave footprint 16 rows x 64B full lines).
// Register-double-buffered with prefetch distance 1 (unroll-by-2, two reg
// sets). A stays shared-in-LDS (computed once per block-tile, 4 evals/thread,
// dbuf + XOR swizzle; SQ_LDS_BANK_CONFLICT == 0 measured R2-R6).
// LDS traffic halves -> MFMA (8.3 us/CU) becomes the pole.
// 128x128 block tile, BK=64, 256 threads = 4 waves (2x2), wave tile 64x64
// via 4x4 of mfma_f32_16x16x32_bf16 (layouts verified R1-R6).
__global__ __launch_bounds__(256, 2) void gemm_fused(
    const float* __restrict__ X,            // [BATCH][ISZ] fp32
    const unsigned short* __restrict__ Bm,  // [OSZ][KDIM] bf16 bits
    unsigned short* __restrict__ Cp,        // [SPLITK][M][N] bf16 partials
    int M, int N, int K)
{
    __shared__ __align__(16) unsigned short As[2][TM * BK];   // 2 x 16 KB

    const int tid  = threadIdx.x;
    const int wave = tid >> 6;
    const int lane = tid & 63;
    const int wm   = (wave >> 1) * 64;      // wave row offset in tile
    const int wn   = (wave & 1) * 64;       // wave col offset in tile

    const int m0 = blockIdx.x * TM;
    const int n0 = blockIdx.y * TN;
    const int kper  = K / SPLITK;           // 1024
    const int kbeg  = blockIdx.z * kper;
    const int niter = kper / BK;            // 16 (even -> unroll-by-2 safe)

    f32x4 acc[4][4] = {};

    const int mrow = lane & 15;             // m/n within 16x16 tile
    const int kc   = lane >> 4;             // 16B-chunk column offset within k

    // A-compute assignment: thread t -> row xr = t>>1, chunk cols xc..xc+3
    const int xr = tid >> 1;
    const int xc = (tid & 1) * 4;

    // B fragment row base pointers (fixed across iters)
    const unsigned short* browp[4];
    #pragma unroll
    for (int ni = 0; ni < 4; ++ni)
        browp[ni] = Bm + (size_t)(n0 + wn + ni * 16 + mrow) * K + kc * 8;

    // 8 B-fragments (2 ks x 4 ni) straight from global into registers
    auto loadB = [&](int k0, bf16x8 (&dst)[8]) {
        #pragma unroll
        for (int ks = 0; ks < 2; ++ks)
            #pragma unroll
            for (int ni = 0; ni < 4; ++ni)
                dst[ks * 4 + ni] = *reinterpret_cast<const bf16x8*>(
                    browp[ni] + k0 + ks * 32);
    };

    // A staging: jacobi8(tanh(x)) for chunk (xr, xc..xc+3) -> As[buf],
    // XOR-swizzled slot = row*8 + (col ^ (row&7))
    auto stageA = [&](int k0, int buf) {
        const int i0 = k0 >> 3;
        float4 xv = *reinterpret_cast<const float4*>(
            X + (size_t)(m0 + xr) * ISZ + i0 + xc);
        const float xs[4] = {xv.x, xv.y, xv.z, xv.w};
        #pragma unroll
        for (int j = 0; j < 4; ++j) {
            // tanh(x) = 1 - 2/(exp(2x)+1); err ~1e-6 << bf16 ulp
            float e  = __expf(2.0f * xs[j]);
            float t  = 1.0f - 2.0f * __builtin_amdgcn_rcpf(e + 1.0f);
            float p0 = 1.0f;
            float p1 = 2.0f * t;
            float p2 = (1.875f     * t) * p1 - 0.75f       * p0;
            float p3 = (1.8666667f * t) * p2 - 0.8f        * p1;
            float p4 = (1.875f     * t) * p3 - 0.83333333f * p2;
            float p5 = (1.8857143f * t) * p4 - 0.85714287f * p3;
            float p6 = (1.8958333f * t) * p5 - 0.875f      * p4;
            float p7 = (1.9047619f * t) * p6 - 0.88888889f * p5;
            uint4 o;
            o.x = (uint32_t)f2bf(p0) | ((uint32_t)f2bf(p1) << 16);
            o.y = (uint32_t)f2bf(p2) | ((uint32_t)f2bf(p3) << 16);
            o.z = (uint32_t)f2bf(p4) | ((uint32_t)f2bf(p5) << 16);
            o.w = (uint32_t)f2bf(p6) | ((uint32_t)f2bf(p7) << 16);
            int slot = xr * 8 + ((xc + j) ^ (xr & 7));
            *reinterpret_cast<uint4*>(&As[buf][0] + (size_t)slot * 8) = o;
        }
    };

    // one k-iteration: prefetch B[kt+1]->nxt and A[kt+1]->As[1-p],
    // then MFMA with cur + As[p]. Barrier drains loads that had the whole
    // compute phase to fly.
    auto mfmaIter = [&](int kt, bf16x8 (&cur)[8], bf16x8 (&nxt)[8]) {
        const int k0 = kbeg + kt * BK;
        const int p  = kt & 1;
        if (kt + 1 < niter) {
            loadB(k0 + BK, nxt);        // global->reg prefetch (vmcnt)
            stageA(k0 + BK, 1 - p);     // VALU + ds_write, overlaps MFMA
        }
        const unsigned short* Ap = &As[p][0];
        #pragma unroll
        for (int ks = 0; ks < 2; ++ks) {
            bf16x8 aF[4];
            const int cbase = ks * 4 + kc;
            #pragma unroll
            for (int mi = 0; mi < 4; ++mi) {
                int r = wm + mi * 16 + mrow;
                int slot = r * 8 + (cbase ^ (r & 7));
                aF[mi] = *reinterpret_cast<const bf16x8*>(Ap + (size_t)slot * 8);
            }
            #pragma unroll
            for (int mi = 0; mi < 4; ++mi)
                #pragma unroll
                for (int ni = 0; ni < 4; ++ni)
                    acc[mi][ni] = __builtin_amdgcn_mfma_f32_16x16x32_bf16(
                        aF[mi], cur[ks * 4 + ni], acc[mi][ni], 0, 0, 0);
        }
        __syncthreads();   // fences As dbuf swap; drains in-flight prefetch
    };

    bf16x8 bufA[8], bufB[8];
    loadB(kbeg, bufA);
    stageA(kbeg, 0);
    __syncthreads();

    for (int kt = 0; kt < niter; kt += 2) {
        mfmaIter(kt,     bufA, bufB);
        mfmaIter(kt + 1, bufB, bufA);
    }

    // bf16 partials, plain stores (no atomics).
    // C/D layout (m89-verified): col = lane&15, row = (lane>>4)*4 + r
    unsigned short* Cz = Cp + (size_t)blockIdx.z * M * N;
    const int orow = blockIdx.x * TM + wm + (lane >> 4) * 4;
    const int ocol = blockIdx.y * TN + wn + (lane & 15);
    #pragma unroll
    for (int mi = 0; mi < 4; ++mi)
        #pragma unroll
        for (int ni = 0; ni < 4; ++ni)
            #pragma unroll
            for (int r = 0; r < 4; ++r)
                Cz[(size_t)(orow + mi * 16 + r) * N + ocol + ni * 16] =
                    f2bf(acc[mi][ni][r]);
}

// out = sum over SPLITK bf16 partials (fp32 accumulate), 4 outputs/thread
__global__ __launch_bounds__(256) void reduce_k(
    const unsigned short* __restrict__ part, float* __restrict__ out, int n4)
{
    int idx = blockIdx.x * 256 + threadIdx.x;
    if (idx >= n4) return;
    const uint2* p = reinterpret_cast<const uint2*>(part);   // 4 bf16 / uint2
    float s0 = 0.f, s1 = 0.f, s2 = 0.f, s3 = 0.f;
    #pragma unroll
    for (int z = 0; z < SPLITK; ++z) {
        uint2 v = p[(size_t)z * n4 + idx];
        s0 += __uint_as_float((v.x & 0xFFFFu) << 16);
        s1 += __uint_as_float(v.x & 0xFFFF0000u);
        s2 += __uint_as_float((v.y & 0xFFFFu) << 16);
        s3 += __uint_as_float(v.y & 0xFFFF0000u);
    }
    float4 o = {s0, s1, s2, s3};
    reinterpret_cast<float4*>(out)[idx] = o;
}

extern "C" void kernel_launch(void* const* d_in, const int* in_sizes, int n_in,
                              void* d_out, int out_size, void* d_ws, size_t ws_size,
                              hipStream_t stream)
{
    const float* x    = (const float*)d_in[0];   // [4096][512]
    const float* coef = (const float*)d_in[1];   // [512][512][8]
    float* out = (float*)d_out;                  // [4096][512]

    // workspace: bf16 partials [SPLITK][4096][512] (16 MB) + coef bf16 (4 MB)
    unsigned short* part  = (unsigned short*)d_ws;
    unsigned short* coefb = part + (size_t)SPLITK * BATCH * OSZ;

    int n4c = (OSZ * KDIM) / 4;                  // 524,288
    convert_bf16<<<(n4c + 255) / 256, 256, 0, stream>>>(coef, coefb, n4c);

    dim3 grid(BATCH / TM, OSZ / TN, SPLITK);     // 32 x 4 x 4 = 512 blocks
    gemm_fused<<<grid, 256, 0, stream>>>(x, coefb, part, BATCH, OSZ, KDIM);

    int n4r = (BATCH * OSZ) / 4;                 // 524,288
    reduce_k<<<(n4r + 255) / 256, 256, 0, stream>>>(part, out, n4r);
}

// Round 8
// 103.079 us; speedup vs baseline: 1.0781x; 1.0781x over previous
//
#include <hip/hip_runtime.h>
#include <stdint.h>

// Problem constants (from reference setup_inputs)
#define BATCH 4096
#define ISZ   512
#define OSZ   512
#define KDIM  4096           // contraction dim: k = i*8 + d

// GEMM tiling
#define TM 128
#define TN 128
#define BK 64
#define SPLITK 8

typedef __bf16 bf16x8 __attribute__((ext_vector_type(8)));
typedef float  f32x4  __attribute__((ext_vector_type(4)));

__device__ __forceinline__ unsigned short f2bf(float f) {
    uint32_t u = __float_as_uint(f);
    u = (u + 0x7FFFu + ((u >> 16) & 1u)) >> 16;
    return (unsigned short)u;
}

// flat fp32 -> bf16 convert (coef already k-contiguous: [O][I][D] -> [O][K])
__global__ __launch_bounds__(256) void convert_bf16(
    const float* __restrict__ src, unsigned short* __restrict__ dst, int n4)
{
    int idx = blockIdx.x * 256 + threadIdx.x;
    if (idx >= n4) return;
    float4 v = reinterpret_cast<const float4*>(src)[idx];
    uint2 o;
    o.x = (uint32_t)f2bf(v.x) | ((uint32_t)f2bf(v.y) << 16);
    o.y = (uint32_t)f2bf(v.z) | ((uint32_t)f2bf(v.w) << 16);
    reinterpret_cast<uint2*>(dst)[idx] = o;
}

// Fused Jacobi + GEMM, bf16 split-K partials with plain stores.
// Evolution: R3 atomics = ~50us TCC serialization (removed). R5 in-register
// A = 2x VALU + dependent chain (reverted). R7 register-B = VGPR cliff
// (reverted). R4==R6 invariant: gemm stuck at 31.3us with EITHER single or
// double buffering at 2 blocks/CU -> binder is barrier-lockstep latency
// exposure, not any pipe BW. R8 attacks occupancy: splitK=8 (1024 blocks),
// single-buffer LDS (32 KB/block), no min-waves bound -> ~3 blocks/CU
// (m97's operating point; independent blocks don't share barriers, so
// co-resident blocks cover each other's vmcnt drains - m114 mechanism).
// Totals (traffic, MFMA, evals) are identical to R6; ONLY co-residency moves.
// 128x128 block tile, BK=64, 256 threads = 4 waves (2x2), wave tile 64x64
// via 4x4 of mfma_f32_16x16x32_bf16 (layouts verified R1-R7).
// LDS: 16B chunks, XOR swizzle slot = row*8 + (c ^ (row&7)) ->
// SQ_LDS_BANK_CONFLICT == 0 measured R2-R7. B via global_load_lds
// (wave-uniform base + lane*16 dest; swizzle applied to per-lane source
// address); A via ds_write_b128 (per-lane scatter fine), same slot map.
__global__ __launch_bounds__(256) void gemm_fused(
    const float* __restrict__ X,            // [BATCH][ISZ] fp32
    const unsigned short* __restrict__ Bm,  // [OSZ][KDIM] bf16 bits
    unsigned short* __restrict__ Cp,        // [SPLITK][M][N] bf16 partials
    int M, int N, int K)
{
    __shared__ __align__(16) unsigned short As[TM * BK];   // 16 KB
    __shared__ __align__(16) unsigned short Bs[TN * BK];   // 16 KB

    const int tid  = threadIdx.x;
    const int wave = tid >> 6;
    const int lane = tid & 63;
    const int wm   = (wave >> 1) * 64;      // wave row offset in tile
    const int wn   = (wave & 1) * 64;       // wave col offset in tile

    const int    m0    = blockIdx.x * TM;
    const size_t baseB = (size_t)blockIdx.y * TN * K;
    const int kper  = K / SPLITK;           // 512
    const int kbeg  = blockIdx.z * kper;
    const int kend  = kbeg + kper;          // 8 iters of BK=64

    f32x4 acc[4][4] = {};

    const int mrow = lane & 15;             // m/n within 16x16 tile
    const int kc   = lane >> 4;             // 16B-chunk column offset within k

    // A-compute assignment: thread t -> row xr = t>>1, chunk cols xc..xc+3
    const int xr = tid >> 1;
    const int xc = (tid & 1) * 4;

    for (int k0 = kbeg; k0 < kend; k0 += BK) {
        // ---- B staging: 128x64 bf16 = 16 KB = 1024 chunks; 256 thr x 4 its
        #pragma unroll
        for (int it = 0; it < 4; ++it) {
            int s    = it * 256 + tid;
            int row  = s >> 3;
            int csrc = (s & 7) ^ (row & 7);
            const unsigned short* gB = Bm + baseB + (size_t)row * K + k0 + csrc * 8;
            unsigned short* lB = Bs + (size_t)(it * 256 + wave * 64) * 8; // uniform
            __builtin_amdgcn_global_load_lds(
                (const __attribute__((address_space(1))) uint32_t*)gB,
                (__attribute__((address_space(3))) uint32_t*)lB, 16, 0, 0);
        }

        // ---- A staging: jacobi8(tanh(x)) for chunk (xr, xc..xc+3)
        {
            const int i0 = k0 >> 3;
            float4 xv = *reinterpret_cast<const float4*>(
                X + (size_t)(m0 + xr) * ISZ + i0 + xc);
            const float xs[4] = {xv.x, xv.y, xv.z, xv.w};
            #pragma unroll
            for (int j = 0; j < 4; ++j) {
                // tanh(x) = 1 - 2/(exp(2x)+1); err ~1e-6 << bf16 ulp
                float e  = __expf(2.0f * xs[j]);
                float t  = 1.0f - 2.0f * __builtin_amdgcn_rcpf(e + 1.0f);
                float p1 = 2.0f * t;
                float p2 = (1.875f     * t) * p1 - 0.75f;
                float p3 = (1.8666667f * t) * p2 - 0.8f        * p1;
                float p4 = (1.875f     * t) * p3 - 0.83333333f * p2;
                float p5 = (1.8857143f * t) * p4 - 0.85714287f * p3;
                float p6 = (1.8958333f * t) * p5 - 0.875f      * p4;
                float p7 = (1.9047619f * t) * p6 - 0.88888889f * p5;
                // native v_cvt_pk_bf16_f32 via (__bf16) casts (R5-proven form)
                bf16x8 v;
                v[0] = (__bf16)1.0f; v[1] = (__bf16)p1;
                v[2] = (__bf16)p2;   v[3] = (__bf16)p3;
                v[4] = (__bf16)p4;   v[5] = (__bf16)p5;
                v[6] = (__bf16)p6;   v[7] = (__bf16)p7;
                int slot = xr * 8 + ((xc + j) ^ (xr & 7));
                *reinterpret_cast<bf16x8*>(As + (size_t)slot * 8) = v;
            }
        }
        __syncthreads();   // drains vmcnt (B DMA) + lgkmcnt (A writes)

        #pragma unroll
        for (int ks = 0; ks < BK; ks += 32) {
            bf16x8 aF[4], bF[4];
            const int cbase = (ks >> 3) + kc;
            #pragma unroll
            for (int mi = 0; mi < 4; ++mi) {
                int r = wm + mi * 16 + mrow;
                int slot = r * 8 + (cbase ^ (r & 7));
                aF[mi] = *reinterpret_cast<const bf16x8*>(As + (size_t)slot * 8);
            }
            #pragma unroll
            for (int ni = 0; ni < 4; ++ni) {
                int r = wn + ni * 16 + mrow;
                int slot = r * 8 + (cbase ^ (r & 7));
                bF[ni] = *reinterpret_cast<const bf16x8*>(Bs + (size_t)slot * 8);
            }
            #pragma unroll
            for (int mi = 0; mi < 4; ++mi)
                #pragma unroll
                for (int ni = 0; ni < 4; ++ni)
                    acc[mi][ni] = __builtin_amdgcn_mfma_f32_16x16x32_bf16(
                        aF[mi], bF[ni], acc[mi][ni], 0, 0, 0);
        }
        __syncthreads();   // fences As/Bs reuse next iter
    }

    // bf16 partials, plain stores (no atomics).
    // C/D layout (m89-verified): col = lane&15, row = (lane>>4)*4 + r
    unsigned short* Cz = Cp + (size_t)blockIdx.z * M * N;
    const int orow = blockIdx.x * TM + wm + (lane >> 4) * 4;
    const int ocol = blockIdx.y * TN + wn + (lane & 15);
    #pragma unroll
    for (int mi = 0; mi < 4; ++mi)
        #pragma unroll
        for (int ni = 0; ni < 4; ++ni)
            #pragma unroll
            for (int r = 0; r < 4; ++r)
                Cz[(size_t)(orow + mi * 16 + r) * N + ocol + ni * 16] =
                    f2bf(acc[mi][ni][r]);
}

// out = sum over SPLITK bf16 partials (fp32 accumulate), 4 outputs/thread
__global__ __launch_bounds__(256) void reduce_k(
    const unsigned short* __restrict__ part, float* __restrict__ out, int n4)
{
    int idx = blockIdx.x * 256 + threadIdx.x;
    if (idx >= n4) return;
    const uint2* p = reinterpret_cast<const uint2*>(part);   // 4 bf16 / uint2
    float s0 = 0.f, s1 = 0.f, s2 = 0.f, s3 = 0.f;
    #pragma unroll
    for (int z = 0; z < SPLITK; ++z) {
        uint2 v = p[(size_t)z * n4 + idx];
        s0 += __uint_as_float((v.x & 0xFFFFu) << 16);
        s1 += __uint_as_float(v.x & 0xFFFF0000u);
        s2 += __uint_as_float((v.y & 0xFFFFu) << 16);
        s3 += __uint_as_float(v.y & 0xFFFF0000u);
    }
    float4 o = {s0, s1, s2, s3};
    reinterpret_cast<float4*>(out)[idx] = o;
}

extern "C" void kernel_launch(void* const* d_in, const int* in_sizes, int n_in,
                              void* d_out, int out_size, void* d_ws, size_t ws_size,
                              hipStream_t stream)
{
    const float* x    = (const float*)d_in[0];   // [4096][512]
    const float* coef = (const float*)d_in[1];   // [512][512][8]
    float* out = (float*)d_out;                  // [4096][512]

    // workspace: bf16 partials [SPLITK][4096][512] (32 MB) + coef bf16 (4 MB)
    unsigned short* part  = (unsigned short*)d_ws;
    unsigned short* coefb = part + (size_t)SPLITK * BATCH * OSZ;

    int n4c = (OSZ * KDIM) / 4;                  // 524,288
    convert_bf16<<<(n4c + 255) / 256, 256, 0, stream>>>(coef, coefb, n4c);

    dim3 grid(BATCH / TM, OSZ / TN, SPLITK);     // 32 x 4 x 8 = 1024 blocks
    gemm_fused<<<grid, 256, 0, stream>>>(x, coefb, part, BATCH, OSZ, KDIM);

    int n4r = (BATCH * OSZ) / 4;                 // 524,288
    reduce_k<<<(n4r + 255) / 256, 256, 0, stream>>>(part, out, n4r);
}

// Round 9
// 102.180 us; speedup vs baseline: 1.0876x; 1.0088x over previous
//
#include <hip/hip_runtime.h>
#include <stdint.h>

// Problem constants (from reference setup_inputs)
#define BATCH 4096
#define ISZ   512
#define OSZ   512
#define KDIM  4096           // contraction dim: k = i*8 + d

// GEMM tiling
#define TM 128
#define TN 128
#define BK 64
#define SPLITK 4

typedef __bf16 bf16x8 __attribute__((ext_vector_type(8)));
typedef float  f32x4  __attribute__((ext_vector_type(4)));

__device__ __forceinline__ unsigned short f2bf(float f) {
    uint32_t u = __float_as_uint(f);
    u = (u + 0x7FFFu + ((u >> 16) & 1u)) >> 16;
    return (unsigned short)u;
}

// Fused prep: one launch does BOTH
//  (a) jac[b][i*8+d] = P_d(tanh(x[b][i]))  (blocks [0, NJAC))
//  (b) coef fp32 -> bf16 flat convert      (blocks [NJAC, NJAC+NCVT))
// R8 post-mortem: fusing jacobi INTO the GEMM k-loop costs ~11us (serial
// X-load + dependent exp/fma chain before each barrier, unhideable);
// streaming it here costs ~6us of HBM-bound work. Un-fused wins.
#define NJAC ((BATCH * ISZ) / 256)          // 8192 blocks
#define NCVT ((OSZ * KDIM) / 4 / 256)       // 2048 blocks
__global__ __launch_bounds__(256) void prep(
    const float* __restrict__ x, unsigned short* __restrict__ jac,
    const float* __restrict__ coef, unsigned short* __restrict__ coefb)
{
    int bid = blockIdx.x;
    if (bid < NJAC) {
        int idx = bid * 256 + threadIdx.x;
        float t  = tanhf(x[idx]);
        float p1 = 2.0f * t;
        float p2 = (1.875f     * t) * p1 - 0.75f;
        float p3 = (1.8666667f * t) * p2 - 0.8f        * p1;
        float p4 = (1.875f     * t) * p3 - 0.83333333f * p2;
        float p5 = (1.8857143f * t) * p4 - 0.85714287f * p3;
        float p6 = (1.8958333f * t) * p5 - 0.875f      * p4;
        float p7 = (1.9047619f * t) * p6 - 0.88888889f * p5;
        uint4 o;
        o.x = 0x3F80u | ((uint32_t)f2bf(p1) << 16);     // bf16(1.0) | p1
        o.y = (uint32_t)f2bf(p2) | ((uint32_t)f2bf(p3) << 16);
        o.z = (uint32_t)f2bf(p4) | ((uint32_t)f2bf(p5) << 16);
        o.w = (uint32_t)f2bf(p6) | ((uint32_t)f2bf(p7) << 16);
        *reinterpret_cast<uint4*>(jac + (size_t)idx * 8) = o;
    } else {
        int idx = (bid - NJAC) * 256 + threadIdx.x;
        float4 v = reinterpret_cast<const float4*>(coef)[idx];
        uint2 o;
        o.x = (uint32_t)f2bf(v.x) | ((uint32_t)f2bf(v.y) << 16);
        o.y = (uint32_t)f2bf(v.z) | ((uint32_t)f2bf(v.w) << 16);
        reinterpret_cast<uint2*>(coefb)[idx] = o;
    }
}

// Pure-DMA GEMM (the measured-fastest k-loop: R2's structure, whose 47us
// included ~27us of atomics -> ~20us loop; every fused-jacobi variant
// R4/R6/R8 sat at 31-33us regardless of buffering/occupancy).
// Cp[z][M][N] = A[M][Kz] * Bm[N][Kz]^T, bf16 partials, plain stores.
// 128x128 block tile, BK=64, 256 threads = 4 waves (2x2), wave tile 64x64
// via 4x4 of mfma_f32_16x16x32_bf16 (layouts verified R1-R8).
// Both A and B staged via global_load_lds width=16 (wave-uniform base +
// lane*16 dest). LDS slots XOR-swizzled: chunk (row,c) at slot
// row*8 + (c ^ (row&7)) -> SQ_LDS_BANK_CONFLICT == 0 measured R2-R8
// (swizzle applied to the per-lane *source* address; permutation stays
// inside a 128B line so global coalescing holds).
// Single-buffered (R4==R6: dbuf neutral), no min-wave bound: VGPR ~88,
// LDS 32 KB -> 4-5 blocks/CU co-resident to cover barrier drains.
__global__ __launch_bounds__(256) void gemm_dma(
    const unsigned short* __restrict__ A,   // [M][K] bf16 bits (jac)
    const unsigned short* __restrict__ Bm,  // [N][K] bf16 bits (coefb)
    unsigned short* __restrict__ Cp,        // [SPLITK][M][N] bf16 partials
    int M, int N, int K)
{
    __shared__ __align__(16) unsigned short As[TM * BK];   // 16 KB
    __shared__ __align__(16) unsigned short Bs[TN * BK];   // 16 KB

    const int tid  = threadIdx.x;
    const int wave = tid >> 6;
    const int lane = tid & 63;
    const int wm   = (wave >> 1) * 64;      // wave row offset in tile
    const int wn   = (wave & 1) * 64;       // wave col offset in tile

    const size_t baseA = (size_t)blockIdx.x * TM * K;
    const size_t baseB = (size_t)blockIdx.y * TN * K;
    const int kper = K / SPLITK;            // 1024
    const int kbeg = blockIdx.z * kper;
    const int kend = kbeg + kper;           // 16 iters of BK=64

    f32x4 acc[4][4] = {};

    const int mrow = lane & 15;             // m/n within 16x16 tile
    const int kc   = lane >> 4;             // 16B-chunk column offset within k

    for (int k0 = kbeg; k0 < kend; k0 += BK) {
        // stage A and B tiles: 128x64 bf16 each = 16 KB = 1024 chunks of 16B;
        // 256 threads x 4 iterations each. slot s = it*256+tid; source chunk
        // row = s>>3, col = (s&7) ^ (row&7); dest = wave-uniform + lane*16.
        #pragma unroll
        for (int it = 0; it < 4; ++it) {
            int s    = it * 256 + tid;
            int row  = s >> 3;
            int csrc = (s & 7) ^ (row & 7);
            const unsigned short* gA = A  + baseA + (size_t)row * K + k0 + csrc * 8;
            const unsigned short* gB = Bm + baseB + (size_t)row * K + k0 + csrc * 8;
            unsigned short* lA = As + (size_t)(it * 256 + wave * 64) * 8;
            unsigned short* lB = Bs + (size_t)(it * 256 + wave * 64) * 8;
            __builtin_amdgcn_global_load_lds(
                (const __attribute__((address_space(1))) uint32_t*)gA,
                (__attribute__((address_space(3))) uint32_t*)lA, 16, 0, 0);
            __builtin_amdgcn_global_load_lds(
                (const __attribute__((address_space(1))) uint32_t*)gB,
                (__attribute__((address_space(3))) uint32_t*)lB, 16, 0, 0);
        }
        __syncthreads();   // drains vmcnt for the DMA

        #pragma unroll
        for (int ks = 0; ks < BK; ks += 32) {
            bf16x8 aF[4], bF[4];
            const int cbase = (ks >> 3) + kc;
            #pragma unroll
            for (int mi = 0; mi < 4; ++mi) {
                int r = wm + mi * 16 + mrow;
                int slot = r * 8 + (cbase ^ (r & 7));
                aF[mi] = *reinterpret_cast<const bf16x8*>(As + (size_t)slot * 8);
            }
            #pragma unroll
            for (int ni = 0; ni < 4; ++ni) {
                int r = wn + ni * 16 + mrow;
                int slot = r * 8 + (cbase ^ (r & 7));
                bF[ni] = *reinterpret_cast<const bf16x8*>(Bs + (size_t)slot * 8);
            }
            #pragma unroll
            for (int mi = 0; mi < 4; ++mi)
                #pragma unroll
                for (int ni = 0; ni < 4; ++ni)
                    acc[mi][ni] = __builtin_amdgcn_mfma_f32_16x16x32_bf16(
                        aF[mi], bF[ni], acc[mi][ni], 0, 0, 0);
        }
        __syncthreads();   // fences As/Bs reuse next iter
    }

    // bf16 partials, plain stores (R3: atomics = ~50us TCC serialization).
    // C/D layout (m89-verified): col = lane&15, row = (lane>>4)*4 + r
    unsigned short* Cz = Cp + (size_t)blockIdx.z * M * N;
    const int orow = blockIdx.x * TM + wm + (lane >> 4) * 4;
    const int ocol = blockIdx.y * TN + wn + (lane & 15);
    #pragma unroll
    for (int mi = 0; mi < 4; ++mi)
        #pragma unroll
        for (int ni = 0; ni < 4; ++ni)
            #pragma unroll
            for (int r = 0; r < 4; ++r)
                Cz[(size_t)(orow + mi * 16 + r) * N + ocol + ni * 16] =
                    f2bf(acc[mi][ni][r]);
}

// out = sum over SPLITK bf16 partials (fp32 accumulate), 4 outputs/thread
__global__ __launch_bounds__(256) void reduce_k(
    const unsigned short* __restrict__ part, float* __restrict__ out, int n4)
{
    int idx = blockIdx.x * 256 + threadIdx.x;
    if (idx >= n4) return;
    const uint2* p = reinterpret_cast<const uint2*>(part);   // 4 bf16 / uint2
    float s0 = 0.f, s1 = 0.f, s2 = 0.f, s3 = 0.f;
    #pragma unroll
    for (int z = 0; z < SPLITK; ++z) {
        uint2 v = p[(size_t)z * n4 + idx];
        s0 += __uint_as_float((v.x & 0xFFFFu) << 16);
        s1 += __uint_as_float(v.x & 0xFFFF0000u);
        s2 += __uint_as_float((v.y & 0xFFFFu) << 16);
        s3 += __uint_as_float(v.y & 0xFFFF0000u);
    }
    float4 o = {s0, s1, s2, s3};
    reinterpret_cast<float4*>(out)[idx] = o;
}

extern "C" void kernel_launch(void* const* d_in, const int* in_sizes, int n_in,
                              void* d_out, int out_size, void* d_ws, size_t ws_size,
                              hipStream_t stream)
{
    const float* x    = (const float*)d_in[0];   // [4096][512]
    const float* coef = (const float*)d_in[1];   // [512][512][8]
    float* out = (float*)d_out;                  // [4096][512]

    // workspace: bf16 partials [SPLITK][4096][512] (16 MB)
    //          + coef bf16 [512][4096] (4 MB) + jac bf16 [4096][4096] (32 MB)
    unsigned short* part  = (unsigned short*)d_ws;
    unsigned short* coefb = part + (size_t)SPLITK * BATCH * OSZ;
    unsigned short* jac   = coefb + (size_t)OSZ * KDIM;

    prep<<<NJAC + NCVT, 256, 0, stream>>>(x, jac, coef, coefb);

    dim3 grid(BATCH / TM, OSZ / TN, SPLITK);     // 32 x 4 x 4 = 512 blocks
    gemm_dma<<<grid, 256, 0, stream>>>(jac, coefb, part, BATCH, OSZ, KDIM);

    int n4r = (BATCH * OSZ) / 4;                 // 524,288
    reduce_k<<<(n4r + 255) / 256, 256, 0, stream>>>(part, out, n4r);
}